// Round 4
// baseline (206.417 us; speedup 1.0000x reference)
//
#include <hip/hip_runtime.h>
#include <hip/hip_bf16.h>

typedef _Float16 f16;
typedef _Float16 half8 __attribute__((ext_vector_type(8)));
typedef _Float16 half4_t __attribute__((ext_vector_type(4)));
typedef float floatx16 __attribute__((ext_vector_type(16)));

// ============================================================
// Kernel 1a: per-(s,conv,m) MLP -> embedding e (128)
// ============================================================
__global__ __launch_bounds__(256) void embed_a(
    const float* __restrict__ seidel,
    const float* __restrict__ m1W1, const float* __restrict__ m1b1,
    const float* __restrict__ m1W2, const float* __restrict__ m1b2,
    const float* __restrict__ m2W1, const float* __restrict__ m2b1,
    const float* __restrict__ m2W2, const float* __restrict__ m2b2,
    float* __restrict__ eout)
{
    int combo = blockIdx.x;                 // (s*2+conv)*4 + m
    int s = combo >> 3, conv = (combo >> 2) & 1, m = combo & 3;
    const float* W1 = conv ? m2W1 : m1W1;
    const float* b1 = conv ? m2b1 : m1b1;
    const float* W2 = conv ? m2W2 : m1W2;
    const float* b2 = conv ? m2b2 : m1b2;
    __shared__ float zs[48], hbuf[128];
    int tid = threadIdx.x;
    if (tid < 48) zs[tid] = seidel[s*48 + tid];
    __syncthreads();
    if (tid < 128) {
        float a = b1[m*128 + tid];
        for (int i = 0; i < 48; ++i) a += zs[i] * W1[(m*48 + i)*128 + tid];
        hbuf[tid] = fmaxf(a, 0.f);
    }
    __syncthreads();
    if (tid < 128) {
        float a = b2[m*128 + tid];
        for (int i = 0; i < 128; ++i) a += hbuf[i] * W2[(m*128 + i)*128 + tid];
        eout[combo*128 + tid] = fmaxf(a, 0.f);
    }
}

// ============================================================
// Kernel 1b: h_in = e @ hyp_w2 + hyp_b2.  grid (32 jtiles, 16 combos)
// ============================================================
__global__ __launch_bounds__(256) void embed_b(
    const float* __restrict__ eout, const float* __restrict__ hw2,
    const float* __restrict__ hb2, float* __restrict__ hin)
{
    int combo = blockIdx.y;
    int j = blockIdx.x*256 + threadIdx.x;   // < 8192
    __shared__ float es[128];
    if (threadIdx.x < 128) es[threadIdx.x] = eout[combo*128 + threadIdx.x];
    __syncthreads();
    float a = hb2[j];
    for (int i = 0; i < 128; ++i) a += es[i] * hw2[(size_t)i*8192 + j];
    hin[(size_t)combo*8192 + j] = a;
}

// ============================================================
// Kernel 2a: transpose hw1 [128 k][4608 j] -> hw1t [4608 j][128 k]
// ============================================================
__global__ void hw1t_kernel(const float* __restrict__ in, float* __restrict__ out)
{
    __shared__ float tile[32][33];
    int j0 = blockIdx.x*32, k0 = blockIdx.y*32;
    int tx = threadIdx.x, ty = threadIdx.y;
    #pragma unroll
    for (int i = 0; i < 4; ++i) tile[ty + i*8][tx] = in[(size_t)(k0 + ty + i*8)*4608 + j0 + tx];
    __syncthreads();
    #pragma unroll
    for (int i = 0; i < 4; ++i) out[(size_t)(j0 + ty + i*8)*128 + k0 + tx] = tile[tx][ty + i*8];
}

// ============================================================
// Kernel 2b: h_fin tile GEMM + coalesced scatter into wtab.
// grid (72 = r*9+tap, 16 combos), 256 threads.
// wtab [sc][r 8][chunk 4][tap 9][co 128][ci 32] f16
// ============================================================
__global__ __launch_bounds__(256) void hfin2_kernel(
    const float* __restrict__ hin, const float* __restrict__ hw1t,
    const float* __restrict__ hb1, f16* __restrict__ wtab)
{
    int c72 = blockIdx.x;
    int combo = blockIdx.y;
    int r = c72 / 9, tap = c72 - r*9;
    int s = combo >> 3, conv = (combo >> 2) & 1, m = combo & 3;
    __shared__ float hl[64][132];
    __shared__ float wt[64][132];
    __shared__ f16 ct[64][72];
    int tid = threadIdx.x;
    const float4* hsrc = (const float4*)(hin + (size_t)combo*8192);
    for (int i = tid; i < 2048; i += 256) {
        int a = i >> 5, kq = i & 31;
        *(float4*)&hl[a][kq*4] = hsrc[i];
    }
    for (int i = tid; i < 2048; i += 256) {
        int b = i >> 5, kq = i & 31;
        *(float4*)&wt[b][kq*4] = *(const float4*)(hw1t + (size_t)(b*72 + c72)*128 + kq*4);
    }
    __syncthreads();
    int ta = tid >> 4, tb = tid & 15;
    int a0 = ta*4, b0 = tb*4;
    float acc[4][4] = {};
    #pragma unroll 4
    for (int k4 = 0; k4 < 32; ++k4) {
        float4 A[4], B[4];
        #pragma unroll
        for (int i = 0; i < 4; ++i) A[i] = *(const float4*)&hl[a0 + i][k4*4];
        #pragma unroll
        for (int i = 0; i < 4; ++i) B[i] = *(const float4*)&wt[b0 + i][k4*4];
        #pragma unroll
        for (int i = 0; i < 4; ++i)
            #pragma unroll
            for (int j2 = 0; j2 < 4; ++j2)
                acc[i][j2] += A[i].x*B[j2].x + A[i].y*B[j2].y + A[i].z*B[j2].z + A[i].w*B[j2].w;
    }
    float bj[4];
    #pragma unroll
    for (int j2 = 0; j2 < 4; ++j2) bj[j2] = hb1[(b0 + j2)*72 + c72];
    #pragma unroll
    for (int i = 0; i < 4; ++i) {
        half4_t v;
        #pragma unroll
        for (int j2 = 0; j2 < 4; ++j2) v[j2] = (f16)(acc[i][j2] + bj[j2]);
        *(half4_t*)&ct[a0 + i][b0] = v;
    }
    __syncthreads();
    {
        int run = tid >> 1, hh = tid & 1;
        int a = run & 63, ch = run >> 6;
        int chunk = (m & 1)*2 + ch;
        int co = (m >> 1)*64 + a;
        size_t base = ((((size_t)(s*2 + conv)*8 + r)*4 + chunk)*9 + tap)*128 + co;
        f16* dst = wtab + base*32 + hh*16;
        const f16* src = &ct[a][ch*32 + hh*16];
        *(half8*)(dst)     = *(const half8*)(src);
        *(half8*)(dst + 8) = *(const half8*)(src + 8);
    }
}

// ============================================================
// Kernel 3: x [s][c][h][w] f32 -> xt [s][w][h][c] f16. grid (256 h, 2 s)
// ============================================================
__global__ __launch_bounds__(256) void xpose_cast2(
    const float* __restrict__ in, f16* __restrict__ out)
{
    __shared__ f16 tileT[128*136];
    int h = blockIdx.x, s = blockIdx.y;
    int tid = threadIdx.x;
    int cg = tid >> 5, q2 = tid & 31;
    const float* src = in + (size_t)s*4194304 + (size_t)h*128;
    for (int pass = 0; pass < 16; ++pass) {
        int c = pass*8 + cg;
        float4 v = *(const float4*)(src + (size_t)c*32768 + q2*4);
        tileT[(q2*4 + 0)*136 + c] = (f16)v.x;
        tileT[(q2*4 + 1)*136 + c] = (f16)v.y;
        tileT[(q2*4 + 2)*136 + c] = (f16)v.z;
        tileT[(q2*4 + 3)*136 + c] = (f16)v.w;
    }
    __syncthreads();
    int ww = tid >> 1, hf = tid & 1;
    const f16* srcT = &tileT[ww*136 + hf*64];
    f16* dst = out + (((size_t)(s*128 + ww)*256 + h)*128) + hf*64;
    #pragma unroll
    for (int i = 0; i < 8; ++i)
        *(float4*)(dst + i*8) = *(const float4*)(srcT + i*8);
}

// ============================================================
// Kernel 5: y2t [s*co][w][h] f32 -> out [s*co][h][w] f32
// ============================================================
__global__ void xpose_out(const float* __restrict__ in, float* __restrict__ out)
{
    __shared__ float tile[32][33];
    int sc = blockIdx.z;
    int w0 = blockIdx.x*32, h0 = blockIdx.y*32;
    int tx = threadIdx.x, ty = threadIdx.y;
    const float* src = in + ((size_t)sc*128 + w0)*256 + h0;
    #pragma unroll
    for (int i = 0; i < 4; ++i) tile[ty + i*8][tx] = src[(size_t)(ty + i*8)*256 + tx];
    __syncthreads();
    float* dst = out + ((size_t)sc*256 + h0)*128 + w0;
    #pragma unroll
    for (int i = 0; i < 4; ++i) dst[(size_t)(ty + i*8)*128 + tx] = tile[tx][ty + i*8];
}

// ============================================================
// Kernel 4: dual-plane MFMA LRI conv + blend + BN + ReLU.
// xin: [s][w 128][h 256][c 128] f16. grid (w 128, s 2), 512 thr = 8 waves.
// Block out = 128co x 256h. Wave (wc=wid&1, wh=wid>>1): 64co x 64h.
// Two accumulator sets (planes r0,r1); blend (1-t)/t in epilogue.
// A-frags load DIRECTLY from global wtab (layout matches fragment layout).
// smX: [3 dj][258 h'][32 ci] f16, 64B rows, slot ^= (row>>1)&3 (2-way free).
// ============================================================
template<int OUT_F16>
__global__ __launch_bounds__(512, 2) void conv_mfma3(
    const f16* __restrict__ xin,
    const f16* __restrict__ wtab,
    int conv,
    const float* __restrict__ bng, const float* __restrict__ bnb,
    void* __restrict__ outp)
{
    int w = blockIdx.x, s = blockIdx.y;
    const f16* xs  = xin  + (size_t)s*4194304;
    const f16* wts = wtab + (size_t)(s*2 + conv)*1179648;

    float fsrc = (w + 0.5f)*0.0625f - 0.5f;
    fsrc = fminf(fmaxf(fsrc, 0.f), 7.f);
    int r0 = (int)fsrc;
    int r1 = min(r0 + 1, 7);
    float t = fsrc - (float)r0;

    __shared__ __align__(16) char sbuf[49536];   // smX: 3*258*64 B; reused as otile
    f16* smX = (f16*)sbuf;

    int tid = threadIdx.x;
    int lane = tid & 63, wid = tid >> 6;
    int wc = wid & 1, wh = wid >> 1;             // wh 0..3
    int l31 = lane & 31, lq = lane >> 5;

    floatx16 acc[2][2][2];                       // [plane][ct][ht]
    #pragma unroll
    for (int p = 0; p < 2; ++p)
        #pragma unroll
        for (int a = 0; a < 2; ++a)
            #pragma unroll
            for (int b = 0; b < 2; ++b) acc[p][a][b] = (floatx16)0.f;

    for (int chunk = 0; chunk < 4; ++chunk) {
        __syncthreads();
        // ---- stage x strips: smX[dj][hp][ci32], swizzled ----
        for (int id = tid; id < 3096; id += 512) {
            int dj = id / 1032;
            int r2 = id - dj*1032;
            int hp = r2 >> 2, cig = r2 & 3;
            int wsg = w + dj - 1;
            half8 v = {};
            if (wsg >= 0 && wsg < 128) {
                int hsrc = (hp - 1) & 255;
                v = *(const half8*)(xs + ((size_t)wsg*256 + hsrc)*128 + chunk*32 + cig*8);
            }
            int boff = (dj*258 + hp)*64 + ((cig*16) ^ (((hp >> 1) & 3) << 4));
            *(half8*)(sbuf + boff) = v;
        }
        __syncthreads();
        // ---- barrier-free tap loop: global af + LDS bf -> 16 MFMA ----
        #pragma unroll 3
        for (int tap = 0; tap < 9; ++tap) {
            int di = tap/3, dj = tap - di*3;
            const f16* w0p = wts + ((((size_t)r0*4 + chunk)*9 + tap) << 12);
            const f16* w1p = wts + ((((size_t)r1*4 + chunk)*9 + tap) << 12);
            half8 af[2][2][2];   // [plane][ct][ks]
            #pragma unroll
            for (int ct2 = 0; ct2 < 2; ++ct2) {
                int co = wc*64 + ct2*32 + l31;
                #pragma unroll
                for (int ks = 0; ks < 2; ++ks) {
                    af[0][ct2][ks] = *(const half8*)(w0p + co*32 + ks*16 + lq*8);
                    af[1][ct2][ks] = *(const half8*)(w1p + co*32 + ks*16 + lq*8);
                }
            }
            half8 bf[2][2];      // [ht][ks]
            #pragma unroll
            for (int ht = 0; ht < 2; ++ht) {
                int hp = wh*64 + ht*32 + l31 + di;
                #pragma unroll
                for (int ks = 0; ks < 2; ++ks) {
                    int boff = (dj*258 + hp)*64 + ((ks*32 + lq*16) ^ (((hp >> 1) & 3) << 4));
                    bf[ht][ks] = *(const half8*)(sbuf + boff);
                }
            }
            #pragma unroll
            for (int ks = 0; ks < 2; ++ks)
                #pragma unroll
                for (int ct2 = 0; ct2 < 2; ++ct2)
                    #pragma unroll
                    for (int ht = 0; ht < 2; ++ht) {
                        acc[0][ct2][ht] = __builtin_amdgcn_mfma_f32_32x32x16_f16(
                            af[0][ct2][ks], bf[ht][ks], acc[0][ct2][ht], 0, 0, 0);
                        acc[1][ct2][ht] = __builtin_amdgcn_mfma_f32_32x32x16_f16(
                            af[1][ct2][ks], bf[ht][ks], acc[1][ct2][ht], 0, 0, 0);
                    }
        }
    }

    // ---- epilogue: blend planes, BN + ReLU, store ----
    float rs = rsqrtf(1.f + 1e-5f);
    float omt = 1.f - t;
    if (OUT_F16) {
        // stage into otile [128 h][136 co] in two h-phases, coalesced store
        f16* otile = (f16*)sbuf;
        f16* yout = (f16*)outp + ((size_t)(s*128 + w)*256)*128;
        #pragma unroll
        for (int ph = 0; ph < 2; ++ph) {
            __syncthreads();
            if ((wh >> 1) == ph) {
                #pragma unroll
                for (int ct2 = 0; ct2 < 2; ++ct2) {
                    #pragma unroll
                    for (int ht = 0; ht < 2; ++ht) {
                        int hrow = (wh & 1)*64 + ht*32 + l31;
                        #pragma unroll
                        for (int rq = 0; rq < 4; ++rq) {
                            int cb = wc*64 + ct2*32 + rq*8 + lq*4;
                            float4 g4 = *(const float4*)&bng[cb];
                            float4 b4 = *(const float4*)&bnb[cb];
                            half4_t v;
                            #pragma unroll
                            for (int e = 0; e < 4; ++e) {
                                float blended = omt*acc[0][ct2][ht][rq*4 + e]
                                              +   t*acc[1][ct2][ht][rq*4 + e];
                                float g = (&g4.x)[e], bb = (&b4.x)[e];
                                v[e] = (f16)fmaxf(blended*g*rs + bb, 0.f);
                            }
                            *(half4_t*)&otile[hrow*136 + cb] = v;
                        }
                    }
                }
            }
            __syncthreads();
            {
                int hrow = tid >> 2, qc = tid & 3;
                const f16* srcT = &otile[hrow*136 + qc*32];
                f16* d = yout + (size_t)(ph*128 + hrow)*128 + qc*32;
                #pragma unroll
                for (int i = 0; i < 4; ++i)
                    *(float4*)(d + i*8) = *(const float4*)(srcT + i*8);
            }
        }
    } else {
        // f32 direct store to [s][co][w][h]
        #pragma unroll
        for (int ct2 = 0; ct2 < 2; ++ct2) {
            #pragma unroll
            for (int ht = 0; ht < 2; ++ht) {
                int hrow = wh*64 + ht*32 + l31;
                #pragma unroll
                for (int r = 0; r < 16; ++r) {
                    int co = wc*64 + ct2*32 + (r & 3) + 8*(r >> 2) + 4*lq;
                    float blended = omt*acc[0][ct2][ht][r] + t*acc[1][ct2][ht][r];
                    float v = fmaxf(blended*bng[co]*rs + bnb[co], 0.f);
                    ((float*)outp)[((size_t)(s*128 + co)*128 + w)*256 + hrow] = v;
                }
            }
        }
    }
}

// ============================================================
extern "C" void kernel_launch(void* const* d_in, const int* in_sizes, int n_in,
                              void* d_out, int out_size, void* d_ws, size_t ws_size,
                              hipStream_t stream) {
    const float* x      = (const float*)d_in[0];
    const float* seidel = (const float*)d_in[1];
    const float* m1W1 = (const float*)d_in[2];
    const float* m1b1 = (const float*)d_in[3];
    const float* m1W2 = (const float*)d_in[4];
    const float* m1b2 = (const float*)d_in[5];
    const float* m2W1 = (const float*)d_in[6];
    const float* m2b1 = (const float*)d_in[7];
    const float* m2W2 = (const float*)d_in[8];
    const float* m2b2 = (const float*)d_in[9];
    const float* hw2  = (const float*)d_in[10];
    const float* hb2  = (const float*)d_in[11];
    const float* hw1  = (const float*)d_in[12];
    const float* hb1  = (const float*)d_in[13];
    const float* bn1g = (const float*)d_in[14];
    const float* bn1b = (const float*)d_in[15];
    const float* bn2g = (const float*)d_in[16];
    const float* bn2b = (const float*)d_in[17];
    float* outp = (float*)d_out;

    char* wsb = (char*)d_ws;
    float* hin  = (float*)wsb;                          // 524288 B
    f16*   wtab = (f16*)(wsb + 524288);                 // 9437184 B
    f16*   xt   = (f16*)(wsb + 9961472);                // 16777216 B
    f16*   y1t  = (f16*)(wsb + 26738688);               // 16777216 B
    float* y2t  = (float*)(wsb + 43515904);             // 33554432 B
    float* eout = (float*)xt;                           // consumed before xt written
    float* hw1t = y2t;                                  // consumed before y2t written

    embed_a<<<16, 256, 0, stream>>>(seidel, m1W1, m1b1, m1W2, m1b2,
                                    m2W1, m2b1, m2W2, m2b2, eout);
    embed_b<<<dim3(32, 16), 256, 0, stream>>>(eout, hw2, hb2, hin);
    hw1t_kernel<<<dim3(144, 4), dim3(32, 8), 0, stream>>>(hw1, hw1t);
    hfin2_kernel<<<dim3(72, 16), 256, 0, stream>>>(hin, hw1t, hb1, wtab);
    xpose_cast2<<<dim3(256, 2), 256, 0, stream>>>(x, xt);
    conv_mfma3<1><<<dim3(128, 2), 512, 0, stream>>>(xt, wtab, 0, bn1g, bn1b, (void*)y1t);
    conv_mfma3<0><<<dim3(128, 2), 512, 0, stream>>>(y1t, wtab, 1, bn2g, bn2b, (void*)y2t);
    xpose_out<<<dim3(4, 8, 256), dim3(32, 8), 0, stream>>>(y2t, outp);
}

// Round 5
// 156.452 us; speedup vs baseline: 1.3194x; 1.3194x over previous
//
#include <hip/hip_runtime.h>
#include <hip/hip_bf16.h>

typedef _Float16 f16;
typedef _Float16 half8 __attribute__((ext_vector_type(8)));
typedef _Float16 half4_t __attribute__((ext_vector_type(4)));
typedef float floatx16 __attribute__((ext_vector_type(16)));

// ============================================================
// Kernel 1a: per-(s,conv,m) MLP -> embedding e (128)
// ============================================================
__global__ __launch_bounds__(256) void embed_a(
    const float* __restrict__ seidel,
    const float* __restrict__ m1W1, const float* __restrict__ m1b1,
    const float* __restrict__ m1W2, const float* __restrict__ m1b2,
    const float* __restrict__ m2W1, const float* __restrict__ m2b1,
    const float* __restrict__ m2W2, const float* __restrict__ m2b2,
    float* __restrict__ eout)
{
    int combo = blockIdx.x;                 // (s*2+conv)*4 + m
    int s = combo >> 3, conv = (combo >> 2) & 1, m = combo & 3;
    const float* W1 = conv ? m2W1 : m1W1;
    const float* b1 = conv ? m2b1 : m1b1;
    const float* W2 = conv ? m2W2 : m1W2;
    const float* b2 = conv ? m2b2 : m1b2;
    __shared__ float zs[48], hbuf[128];
    int tid = threadIdx.x;
    if (tid < 48) zs[tid] = seidel[s*48 + tid];
    __syncthreads();
    if (tid < 128) {
        float a = b1[m*128 + tid];
        for (int i = 0; i < 48; ++i) a += zs[i] * W1[(m*48 + i)*128 + tid];
        hbuf[tid] = fmaxf(a, 0.f);
    }
    __syncthreads();
    if (tid < 128) {
        float a = b2[m*128 + tid];
        for (int i = 0; i < 128; ++i) a += hbuf[i] * W2[(m*128 + i)*128 + tid];
        eout[combo*128 + tid] = fmaxf(a, 0.f);
    }
}

// ============================================================
// Kernel 1b: h_in = e @ hyp_w2 + hyp_b2.  grid (32 jtiles, 16 combos)
// ============================================================
__global__ __launch_bounds__(256) void embed_b(
    const float* __restrict__ eout, const float* __restrict__ hw2,
    const float* __restrict__ hb2, float* __restrict__ hin)
{
    int combo = blockIdx.y;
    int j = blockIdx.x*256 + threadIdx.x;   // < 8192
    __shared__ float es[128];
    if (threadIdx.x < 128) es[threadIdx.x] = eout[combo*128 + threadIdx.x];
    __syncthreads();
    float a = hb2[j];
    for (int i = 0; i < 128; ++i) a += es[i] * hw2[(size_t)i*8192 + j];
    hin[(size_t)combo*8192 + j] = a;
}

// ============================================================
// Kernel 2a: transpose hw1 [128 k][4608 j] -> hw1t [4608 j][128 k]
// ============================================================
__global__ void hw1t_kernel(const float* __restrict__ in, float* __restrict__ out)
{
    __shared__ float tile[32][33];
    int j0 = blockIdx.x*32, k0 = blockIdx.y*32;
    int tx = threadIdx.x, ty = threadIdx.y;
    #pragma unroll
    for (int i = 0; i < 4; ++i) tile[ty + i*8][tx] = in[(size_t)(k0 + ty + i*8)*4608 + j0 + tx];
    __syncthreads();
    #pragma unroll
    for (int i = 0; i < 4; ++i) out[(size_t)(j0 + ty + i*8)*128 + k0 + tx] = tile[tx][ty + i*8];
}

// ============================================================
// Kernel 2b: h_fin tile GEMM + coalesced scatter into wtab.
// grid (72 = r*9+tap, 16 combos), 256 threads.
// wtab [sc][r 8][chunk 4][tap 9][co 128][ci 32] f16
// ============================================================
__global__ __launch_bounds__(256) void hfin2_kernel(
    const float* __restrict__ hin, const float* __restrict__ hw1t,
    const float* __restrict__ hb1, f16* __restrict__ wtab)
{
    int c72 = blockIdx.x;
    int combo = blockIdx.y;
    int r = c72 / 9, tap = c72 - r*9;
    int s = combo >> 3, conv = (combo >> 2) & 1, m = combo & 3;
    __shared__ float hl[64][132];
    __shared__ float wt[64][132];
    __shared__ f16 ct[64][72];
    int tid = threadIdx.x;
    const float4* hsrc = (const float4*)(hin + (size_t)combo*8192);
    for (int i = tid; i < 2048; i += 256) {
        int a = i >> 5, kq = i & 31;
        *(float4*)&hl[a][kq*4] = hsrc[i];
    }
    for (int i = tid; i < 2048; i += 256) {
        int b = i >> 5, kq = i & 31;
        *(float4*)&wt[b][kq*4] = *(const float4*)(hw1t + (size_t)(b*72 + c72)*128 + kq*4);
    }
    __syncthreads();
    int ta = tid >> 4, tb = tid & 15;
    int a0 = ta*4, b0 = tb*4;
    float acc[4][4] = {};
    #pragma unroll 4
    for (int k4 = 0; k4 < 32; ++k4) {
        float4 A[4], B[4];
        #pragma unroll
        for (int i = 0; i < 4; ++i) A[i] = *(const float4*)&hl[a0 + i][k4*4];
        #pragma unroll
        for (int i = 0; i < 4; ++i) B[i] = *(const float4*)&wt[b0 + i][k4*4];
        #pragma unroll
        for (int i = 0; i < 4; ++i)
            #pragma unroll
            for (int j2 = 0; j2 < 4; ++j2)
                acc[i][j2] += A[i].x*B[j2].x + A[i].y*B[j2].y + A[i].z*B[j2].z + A[i].w*B[j2].w;
    }
    float bj[4];
    #pragma unroll
    for (int j2 = 0; j2 < 4; ++j2) bj[j2] = hb1[(b0 + j2)*72 + c72];
    #pragma unroll
    for (int i = 0; i < 4; ++i) {
        half4_t v;
        #pragma unroll
        for (int j2 = 0; j2 < 4; ++j2) v[j2] = (f16)(acc[i][j2] + bj[j2]);
        *(half4_t*)&ct[a0 + i][b0] = v;
    }
    __syncthreads();
    {
        int run = tid >> 1, hh = tid & 1;
        int a = run & 63, ch = run >> 6;
        int chunk = (m & 1)*2 + ch;
        int co = (m >> 1)*64 + a;
        size_t base = ((((size_t)(s*2 + conv)*8 + r)*4 + chunk)*9 + tap)*128 + co;
        f16* dst = wtab + base*32 + hh*16;
        const f16* src = &ct[a][ch*32 + hh*16];
        *(half8*)(dst)     = *(const half8*)(src);
        *(half8*)(dst + 8) = *(const half8*)(src + 8);
    }
}

// ============================================================
// Kernel 3: x [s][c][h][w] f32 -> xt [s][w][h][c] f16. grid (256 h, 2 s)
// ============================================================
__global__ __launch_bounds__(256) void xpose_cast2(
    const float* __restrict__ in, f16* __restrict__ out)
{
    __shared__ f16 tileT[128*136];
    int h = blockIdx.x, s = blockIdx.y;
    int tid = threadIdx.x;
    int cg = tid >> 5, q2 = tid & 31;
    const float* src = in + (size_t)s*4194304 + (size_t)h*128;
    for (int pass = 0; pass < 16; ++pass) {
        int c = pass*8 + cg;
        float4 v = *(const float4*)(src + (size_t)c*32768 + q2*4);
        tileT[(q2*4 + 0)*136 + c] = (f16)v.x;
        tileT[(q2*4 + 1)*136 + c] = (f16)v.y;
        tileT[(q2*4 + 2)*136 + c] = (f16)v.z;
        tileT[(q2*4 + 3)*136 + c] = (f16)v.w;
    }
    __syncthreads();
    int ww = tid >> 1, hf = tid & 1;
    const f16* srcT = &tileT[ww*136 + hf*64];
    f16* dst = out + (((size_t)(s*128 + ww)*256 + h)*128) + hf*64;
    #pragma unroll
    for (int i = 0; i < 8; ++i)
        *(float4*)(dst + i*8) = *(const float4*)(srcT + i*8);
}

// ============================================================
// Kernel 5: y2t [s*co][w][h] f32 -> out [s*co][h][w] f32
// ============================================================
__global__ void xpose_out(const float* __restrict__ in, float* __restrict__ out)
{
    __shared__ float tile[32][33];
    int sc = blockIdx.z;
    int w0 = blockIdx.x*32, h0 = blockIdx.y*32;
    int tx = threadIdx.x, ty = threadIdx.y;
    const float* src = in + ((size_t)sc*128 + w0)*256 + h0;
    #pragma unroll
    for (int i = 0; i < 4; ++i) tile[ty + i*8][tx] = src[(size_t)(ty + i*8)*256 + tx];
    __syncthreads();
    float* dst = out + ((size_t)sc*256 + h0)*128 + w0;
    #pragma unroll
    for (int i = 0; i < 4; ++i) dst[(size_t)(ty + i*8)*128 + tx] = tile[tx][ty + i*8];
}

// ============================================================
// Kernel 4: MFMA LRI conv + BN + ReLU, v4.
// xin: [s][w 128][h 256][c 128] f16. grid (bx 128, s 2), 512 thr = 8 waves.
// w = (bx&7)*16 + bx>>3  (XCD-locality swizzle: XCD x owns w in [16x,16x+16)).
// Block out = 128co x 256h; wave (wc=wid&1, wh=wid>>1): 64co x 64h, 2x2 of 32x32.
// Per ci-32 chunk: stage ALL 9 taps of lerped weights + x strips in LDS
// (operand-major, conflict-free), then 9 taps barrier-free: 8 ds_read_b128
// + 8 MFMA per wave per tap.
// smW: [tap 9][kpart 4][co 128][8 f16]  (73728 B)
// smX: [dj 3][kpart 4][hp 258][8 f16]   (49536 B)
// ============================================================
template<int OUT_F16>
__global__ __launch_bounds__(512, 2) void conv_mfma4(
    const f16* __restrict__ xin,
    const f16* __restrict__ wtab,
    int conv,
    const float* __restrict__ bng, const float* __restrict__ bnb,
    void* __restrict__ outp)
{
    int bx = blockIdx.x, s = blockIdx.y;
    int w = ((bx & 7) << 4) | (bx >> 3);
    const f16* xs  = xin  + (size_t)s*4194304;
    const f16* wts = wtab + (size_t)(s*2 + conv)*1179648;

    float fsrc = (w + 0.5f)*0.0625f - 0.5f;
    fsrc = fminf(fmaxf(fsrc, 0.f), 7.f);
    int r0 = (int)fsrc;
    int r1 = min(r0 + 1, 7);
    float t = fsrc - (float)r0;
    f16 th = (f16)t;

    __shared__ __align__(16) char sbuf[123264];
    f16* smW = (f16*)sbuf;                 // [9][4][128][8]
    f16* smX = (f16*)(sbuf + 73728);       // [3][4][258][8]

    int tid = threadIdx.x;
    int lane = tid & 63, wid = tid >> 6;
    int wc = wid & 1, wh = wid >> 1;       // wh 0..3
    int l31 = lane & 31, lq = lane >> 5;

    floatx16 acc[2][2];
    #pragma unroll
    for (int a = 0; a < 2; ++a)
        #pragma unroll
        for (int b = 0; b < 2; ++b) acc[a][b] = (floatx16)0.f;

    int spart = tid >> 7, sco = tid & 127;     // smW staging coords

    for (int chunk = 0; chunk < 4; ++chunk) {
        __syncthreads();
        // ---- stage x strips: smX[dj][part][hp][8] ----
        #pragma unroll
        for (int it = 0; it < 7; ++it) {
            int id = tid + it*512;
            if (id < 3096) {
                int dj = id / 1032;
                int r2 = id - dj*1032;
                int part = r2 & 3, hp = r2 >> 2;
                int wsg = w + dj - 1;
                half8 v = {};
                if (wsg >= 0 && wsg < 128) {
                    int hsrc = (hp - 1) & 255;
                    v = *(const half8*)(xs + ((size_t)wsg*256 + hsrc)*128 + chunk*32 + part*8);
                }
                *(half8*)(smX + (size_t)((dj*4 + part)*258 + hp)*8) = v;
            }
        }
        // ---- stage lerped weights: smW[tap][part][co][8] ----
        #pragma unroll
        for (int tap = 0; tap < 9; ++tap) {
            size_t o0 = (((size_t)(r0*4 + chunk)*9 + tap)*128 + sco)*32 + spart*8;
            size_t o1 = (((size_t)(r1*4 + chunk)*9 + tap)*128 + sco)*32 + spart*8;
            half8 a = *(const half8*)(wts + o0);
            half8 b = *(const half8*)(wts + o1);
            half8 o = a + (b - a)*th;
            *(half8*)(smW + (size_t)((tap*4 + spart)*128 + sco)*8) = o;
        }
        __syncthreads();
        // ---- 9 taps, barrier-free ----
        #pragma unroll
        for (int tap = 0; tap < 9; ++tap) {
            int di = tap/3, dj = tap - di*3;
            half8 af[2][2], bf[2][2];      // [ks][ct] / [ks][ht]
            #pragma unroll
            for (int ks = 0; ks < 2; ++ks) {
                #pragma unroll
                for (int ct = 0; ct < 2; ++ct)
                    af[ks][ct] = *(const half8*)(smW +
                        (size_t)((tap*4 + ks*2 + lq)*128 + wc*64 + ct*32 + l31)*8);
                #pragma unroll
                for (int ht = 0; ht < 2; ++ht)
                    bf[ks][ht] = *(const half8*)(smX +
                        (size_t)((dj*4 + ks*2 + lq)*258 + wh*64 + ht*32 + l31 + di)*8);
            }
            #pragma unroll
            for (int ks = 0; ks < 2; ++ks)
                #pragma unroll
                for (int ct = 0; ct < 2; ++ct)
                    #pragma unroll
                    for (int ht = 0; ht < 2; ++ht)
                        acc[ct][ht] = __builtin_amdgcn_mfma_f32_32x32x16_f16(
                            af[ks][ct], bf[ks][ht], acc[ct][ht], 0, 0, 0);
        }
    }

    // ---- epilogue: BN + ReLU, store ----
    float rs = rsqrtf(1.f + 1e-5f);
    if (OUT_F16) {
        f16* otile = (f16*)sbuf;           // [128][136]
        f16* yout = (f16*)outp + ((size_t)(s*128 + w)*256)*128;
        #pragma unroll
        for (int ph = 0; ph < 2; ++ph) {
            __syncthreads();
            if ((wh >> 1) == ph) {
                #pragma unroll
                for (int ct = 0; ct < 2; ++ct) {
                    #pragma unroll
                    for (int ht = 0; ht < 2; ++ht) {
                        int hrow = (wh & 1)*64 + ht*32 + l31;
                        #pragma unroll
                        for (int rq = 0; rq < 4; ++rq) {
                            int cb = wc*64 + ct*32 + rq*8 + lq*4;
                            float4 g4 = *(const float4*)&bng[cb];
                            float4 b4 = *(const float4*)&bnb[cb];
                            half4_t v;
                            #pragma unroll
                            for (int e = 0; e < 4; ++e) {
                                float g = (&g4.x)[e], bb = (&b4.x)[e];
                                v[e] = (f16)fmaxf(acc[ct][ht][rq*4 + e]*g*rs + bb, 0.f);
                            }
                            *(half4_t*)&otile[hrow*136 + cb] = v;
                        }
                    }
                }
            }
            __syncthreads();
            {
                int hrow = tid >> 2, qc = tid & 3;
                const f16* srcT = &otile[hrow*136 + qc*32];
                f16* d = yout + (size_t)(ph*128 + hrow)*128 + qc*32;
                #pragma unroll
                for (int i = 0; i < 4; ++i)
                    *(float4*)(d + i*8) = *(const float4*)(srcT + i*8);
            }
        }
    } else {
        #pragma unroll
        for (int ct = 0; ct < 2; ++ct) {
            #pragma unroll
            for (int ht = 0; ht < 2; ++ht) {
                int hrow = wh*64 + ht*32 + l31;
                #pragma unroll
                for (int r = 0; r < 16; ++r) {
                    int co = wc*64 + ct*32 + (r & 3) + 8*(r >> 2) + 4*lq;
                    float v = fmaxf(acc[ct][ht][r]*bng[co]*rs + bnb[co], 0.f);
                    ((float*)outp)[((size_t)(s*128 + co)*128 + w)*256 + hrow] = v;
                }
            }
        }
    }
}

// ============================================================
extern "C" void kernel_launch(void* const* d_in, const int* in_sizes, int n_in,
                              void* d_out, int out_size, void* d_ws, size_t ws_size,
                              hipStream_t stream) {
    const float* x      = (const float*)d_in[0];
    const float* seidel = (const float*)d_in[1];
    const float* m1W1 = (const float*)d_in[2];
    const float* m1b1 = (const float*)d_in[3];
    const float* m1W2 = (const float*)d_in[4];
    const float* m1b2 = (const float*)d_in[5];
    const float* m2W1 = (const float*)d_in[6];
    const float* m2b1 = (const float*)d_in[7];
    const float* m2W2 = (const float*)d_in[8];
    const float* m2b2 = (const float*)d_in[9];
    const float* hw2  = (const float*)d_in[10];
    const float* hb2  = (const float*)d_in[11];
    const float* hw1  = (const float*)d_in[12];
    const float* hb1  = (const float*)d_in[13];
    const float* bn1g = (const float*)d_in[14];
    const float* bn1b = (const float*)d_in[15];
    const float* bn2g = (const float*)d_in[16];
    const float* bn2b = (const float*)d_in[17];
    float* outp = (float*)d_out;

    char* wsb = (char*)d_ws;
    float* hin  = (float*)wsb;                          // 524288 B
    f16*   wtab = (f16*)(wsb + 524288);                 // 9437184 B
    f16*   xt   = (f16*)(wsb + 9961472);                // 16777216 B
    f16*   y1t  = (f16*)(wsb + 26738688);               // 16777216 B
    float* y2t  = (float*)(wsb + 43515904);             // 33554432 B
    float* eout = (float*)xt;                           // consumed before xt written
    float* hw1t = y2t;                                  // consumed before y2t written

    embed_a<<<16, 256, 0, stream>>>(seidel, m1W1, m1b1, m1W2, m1b2,
                                    m2W1, m2b1, m2W2, m2b2, eout);
    embed_b<<<dim3(32, 16), 256, 0, stream>>>(eout, hw2, hb2, hin);
    hw1t_kernel<<<dim3(144, 4), dim3(32, 8), 0, stream>>>(hw1, hw1t);
    hfin2_kernel<<<dim3(72, 16), 256, 0, stream>>>(hin, hw1t, hb1, wtab);
    xpose_cast2<<<dim3(256, 2), 256, 0, stream>>>(x, xt);
    conv_mfma4<1><<<dim3(128, 2), 512, 0, stream>>>(xt, wtab, 0, bn1g, bn1b, (void*)y1t);
    conv_mfma4<0><<<dim3(128, 2), 512, 0, stream>>>(y1t, wtab, 1, bn2g, bn2b, (void*)y2t);
    xpose_out<<<dim3(4, 8, 256), dim3(32, 8), 0, stream>>>(y2t, outp);
}